// Round 2
// baseline (1995.067 us; speedup 1.0000x reference)
//
#include <hip/hip_runtime.h>
#include <math.h>

#define L_SEQ 512
#define BATCH 128
#define DIN   128
#define HID   512
#define NOUT  5

// ---------------------------------------------------------------------------
// Tiled fp32 GEMM: C[M,N] = A[M,K] * B[K,N]   (row-major, dims % tile == 0)
// 128x128 block tile, BK=16, 256 threads, 8x8 micro-tile per thread.
// ---------------------------------------------------------------------------
#define BM 128
#define BN 128
#define BKK 16

__global__ __launch_bounds__(256, 2)
void gemm_f32(const float* __restrict__ A, const float* __restrict__ B,
              float* __restrict__ C, int M, int N, int K) {
  __shared__ float As[BKK][BM + 4];
  __shared__ float Bs[BKK][BN + 4];

  const int nbx = N / BN;
  const int bx = blockIdx.x % nbx;
  const int by = blockIdx.x / nbx;
  const int tid = threadIdx.x;

  const int tx = tid & 15;   // N direction (8 cols each)
  const int ty = tid >> 4;   // M direction (8 rows each)

  const int arow = tid >> 1;
  const int acol = (tid & 1) * 8;
  const int brow = tid >> 4;
  const int bcol = (tid & 15) * 8;

  const float* Aptr = A + (size_t)(by * BM + arow) * K + acol;
  const float* Bptr = B + (size_t)brow * N + (size_t)bx * BN + bcol;

  float acc[8][8];
#pragma unroll
  for (int i = 0; i < 8; ++i)
#pragma unroll
    for (int j = 0; j < 8; ++j) acc[i][j] = 0.f;

  for (int kt = 0; kt < K; kt += BKK) {
    float4 a0 = *(const float4*)(Aptr + kt);
    float4 a1 = *(const float4*)(Aptr + kt + 4);
    float4 b0 = *(const float4*)(Bptr + (size_t)kt * N);
    float4 b1 = *(const float4*)(Bptr + (size_t)kt * N + 4);

    __syncthreads();
    As[acol + 0][arow] = a0.x; As[acol + 1][arow] = a0.y;
    As[acol + 2][arow] = a0.z; As[acol + 3][arow] = a0.w;
    As[acol + 4][arow] = a1.x; As[acol + 5][arow] = a1.y;
    As[acol + 6][arow] = a1.z; As[acol + 7][arow] = a1.w;
    *(float4*)&Bs[brow][bcol]     = b0;
    *(float4*)&Bs[brow][bcol + 4] = b1;
    __syncthreads();

#pragma unroll
    for (int k = 0; k < BKK; ++k) {
      float a[8], b[8];
      *(float4*)&a[0] = *(const float4*)&As[k][ty * 8];
      *(float4*)&a[4] = *(const float4*)&As[k][ty * 8 + 4];
      *(float4*)&b[0] = *(const float4*)&Bs[k][tx * 8];
      *(float4*)&b[4] = *(const float4*)&Bs[k][tx * 8 + 4];
#pragma unroll
      for (int i = 0; i < 8; ++i)
#pragma unroll
        for (int j = 0; j < 8; ++j)
          acc[i][j] = fmaf(a[i], b[j], acc[i][j]);
    }
  }

  float* Cptr = C + (size_t)(by * BM + ty * 8) * N + (size_t)bx * BN + tx * 8;
#pragma unroll
  for (int i = 0; i < 8; ++i) {
    *(float4*)(Cptr + (size_t)i * N)     = *(float4*)&acc[i][0];
    *(float4*)(Cptr + (size_t)i * N + 4) = *(float4*)&acc[i][4];
  }
}

// ---------------------------------------------------------------------------
__device__ __forceinline__ float sigmoidf_(float x) {
  return 1.f / (1.f + expf(-x));
}

// Layer-0 scan over one time chunk; carries c state in global memory.
// One thread per (b,h) chain; writes full h for every step in the chunk.
__global__ __launch_bounds__(256)
void sru_scan0_chunk(const float* __restrict__ U, const float* __restrict__ v,
                     const float* __restrict__ bias, float* __restrict__ hout,
                     float* __restrict__ cstate, int Tc) {
  const int j = blockIdx.x * blockDim.x + threadIdx.x;  // 0 .. BATCH*HID-1
  const int h = j & (HID - 1);
  const float vf = v[h],    vr = v[HID + h];
  const float bf = bias[h], br = bias[HID + h];

  const float* p = U + (size_t)(j >> 9) * (3 * HID) + h;
  const size_t strideT = (size_t)BATCH * 3 * HID;
  float* hp = hout + (size_t)(j >> 9) * HID + h;
  const size_t hstride = (size_t)BATCH * HID;

  float c = cstate[j];
  for (int t = 0; t < Tc; ++t) {
    const float u0 = p[0], u1 = p[HID], u2 = p[2 * HID];
    p += strideT;
    const float f = sigmoidf_(u1 + vf * c + bf);
    const float r = sigmoidf_(u2 + vr * c + br);
    c = f * c + (1.f - f) * u0;
    hp[(size_t)t * hstride] = r * c;
  }
  cstate[j] = c;
}

// Layer-1 scan over one chunk: only the global last step needs r / h output.
__global__ __launch_bounds__(256)
void sru_scan1_chunk(const float* __restrict__ U, const float* __restrict__ v,
                     const float* __restrict__ bias, float* __restrict__ cstate,
                     float* __restrict__ hlast, int Tc, int lastT) {
  const int j = blockIdx.x * blockDim.x + threadIdx.x;
  const int h = j & (HID - 1);
  const float vf = v[h],    vr = v[HID + h];
  const float bf = bias[h], br = bias[HID + h];

  const float* p = U + (size_t)(j >> 9) * (3 * HID) + h;
  const size_t strideT = (size_t)BATCH * 3 * HID;

  float c = cstate[j];
  for (int t = 0; t < Tc; ++t) {
    const float u0 = p[0], u1 = p[HID];
    const float f = sigmoidf_(u1 + vf * c + bf);
    const float cn = f * c + (1.f - f) * u0;
    if (t == lastT) {  // uniform branch; taken once in the whole sequence
      const float u2 = p[2 * HID];
      const float r = sigmoidf_(u2 + vr * c + br);
      hlast[j] = r * cn;
    }
    c = cn;
    p += strideT;
  }
  cstate[j] = c;
}

// ---------------------------------------------------------------------------
__global__ __launch_bounds__(256)
void zero_f32(float* __restrict__ p, int n) {
  const int i = blockIdx.x * blockDim.x + threadIdx.x;
  if (i < n) p[i] = 0.f;
}

__global__ __launch_bounds__(256)
void fc_head(const float* __restrict__ h, const float* __restrict__ w,
             const float* __restrict__ bias, float* __restrict__ out) {
  const int gid  = blockIdx.x * blockDim.x + threadIdx.x;
  const int wid  = gid >> 6;
  const int lane = threadIdx.x & 63;
  if (wid >= BATCH * NOUT) return;
  const int b = wid / NOUT;
  const int o = wid % NOUT;

  float s = 0.f;
#pragma unroll
  for (int k = lane; k < HID; k += 64)
    s += h[(size_t)b * HID + k] * w[(size_t)o * HID + k];
#pragma unroll
  for (int off = 32; off > 0; off >>= 1) s += __shfl_down(s, off);
  if (lane == 0) out[(size_t)b * NOUT + o] = s + bias[o];
}

// ---------------------------------------------------------------------------
extern "C" void kernel_launch(void* const* d_in, const int* in_sizes, int n_in,
                              void* d_out, int out_size, void* d_ws, size_t ws_size,
                              hipStream_t stream) {
  const float* x    = (const float*)d_in[0];
  const float* W0   = (const float*)d_in[1];
  const float* v0   = (const float*)d_in[2];
  const float* b0   = (const float*)d_in[3];
  const float* W1   = (const float*)d_in[4];
  const float* v1   = (const float*)d_in[5];
  const float* b1   = (const float*)d_in[6];
  const float* fcw  = (const float*)d_in[7];
  const float* fcb  = (const float*)d_in[8];
  float* out = (float*)d_out;

  // Pick the largest time-chunk whose workspace footprint fits ws_size.
  // footprint(Tc) = U0c + U1c (Tc*B*3H each) + h1c (Tc*B*H) + c0+c1+h2 (B*H each)
  int Tc = 128;
  while (Tc > 4) {
    size_t need = ((size_t)Tc * BATCH * 3 * HID * 2 +
                   (size_t)Tc * BATCH * HID +
                   3 * (size_t)BATCH * HID) * sizeof(float) + 1024;
    if (need <= ws_size) break;
    Tc >>= 1;
  }
  const int NC = L_SEQ / Tc;

  float* U0c = (float*)d_ws;                       // Tc*B*3H
  float* U1c = U0c + (size_t)Tc * BATCH * 3 * HID; // Tc*B*3H
  float* h1c = U1c + (size_t)Tc * BATCH * 3 * HID; // Tc*B*H
  float* c0  = h1c + (size_t)Tc * BATCH * HID;     // B*H
  float* c1  = c0  + (size_t)BATCH * HID;          // B*H
  float* h2  = c1  + (size_t)BATCH * HID;          // B*H

  const int Mc = Tc * BATCH;
  const int gemm_grid = (Mc / BM) * (3 * HID / BN);
  const int scan_grid = (BATCH * HID) / 256;
  const int fc_grid   = (BATCH * NOUT * 64 + 255) / 256;

  // zero the carried cell states (ws is poisoned before every call)
  zero_f32<<<(2 * BATCH * HID) / 256, 256, 0, stream>>>(c0, 2 * BATCH * HID);

  for (int ch = 0; ch < NC; ++ch) {
    const int t0 = ch * Tc;
    gemm_f32<<<gemm_grid, 256, 0, stream>>>(
        x + (size_t)t0 * BATCH * DIN, W0, U0c, Mc, 3 * HID, DIN);
    sru_scan0_chunk<<<scan_grid, 256, 0, stream>>>(U0c, v0, b0, h1c, c0, Tc);
    gemm_f32<<<gemm_grid, 256, 0, stream>>>(h1c, W1, U1c, Mc, 3 * HID, HID);
    sru_scan1_chunk<<<scan_grid, 256, 0, stream>>>(
        U1c, v1, b1, c1, h2, Tc, (ch == NC - 1) ? Tc - 1 : -1);
  }
  fc_head<<<fc_grid, 256, 0, stream>>>(h2, fcw, fcb, out);
}

// Round 3
// 767.724 us; speedup vs baseline: 2.5987x; 2.5987x over previous
//
#include <hip/hip_runtime.h>
#include <math.h>

#define L_SEQ 512
#define BATCH 128
#define DIN   128
#define HID   512
#define NOUT  5

typedef unsigned short u16;
typedef unsigned int   u32;
typedef __attribute__((ext_vector_type(8))) short short8;
typedef __attribute__((ext_vector_type(4))) float f32x4;

// ---------------------------------------------------------------------------
// bf16 split helpers (RNE). Inputs are well-behaved (no NaN/Inf).
// ---------------------------------------------------------------------------
__device__ __forceinline__ u16 f2bf(float x) {
  u32 u = __float_as_uint(x);
  return (u16)((u + 0x7fffu + ((u >> 16) & 1u)) >> 16);
}
__device__ __forceinline__ float bf2f(u16 s) {
  return __uint_as_float(((u32)s) << 16);
}
__device__ __forceinline__ void gload16(const void* g, void* l) {
  __builtin_amdgcn_global_load_lds(
      (const __attribute__((address_space(1))) u32*)g,
      (__attribute__((address_space(3))) u32*)l, 16, 0, 0);
}

// ---------------------------------------------------------------------------
// Split-bf16 MFMA GEMM:  C[M,N] = A[M,K] * BT[N,K]^T   (fp32-accurate via
// Ah*Bh + Ah*Bl + Al*Bh).  128x128 tile, BK=32, 4 waves, 16x16x32 MFMA.
// LDS staged with global_load_lds(16B) + XOR-swizzled global source so the
// fragment ds_read_b128s are bank-conflict-free (swizzle: slot ^= (row>>1)&3).
// ---------------------------------------------------------------------------
__global__ __launch_bounds__(256, 2)
void gemm_bf16x3(const u16* __restrict__ Ah, const u16* __restrict__ Al,
                 const u16* __restrict__ Bh, const u16* __restrict__ Bl,
                 float* __restrict__ C, int M, int N, int K) {
  __shared__ u16 sAh[4096], sAl[4096], sBh[4096], sBl[4096];

  const int nbx = N >> 7;
  const int bx = blockIdx.x % nbx;
  const int by = blockIdx.x / nbx;
  const int tid = threadIdx.x;
  const int wid = tid >> 6, lane = tid & 63;

  // staging: thread covers 16B = 8 u16; round r covers tile rows [r*64, r*64+64)
  const int srow = tid >> 2;                       // tile row in round 0
  const int sw = (tid & 3) ^ ((srow >> 1) & 3);    // swizzled 16B slot (same both rounds)
  const size_t aoff0 = (size_t)(by * 128 + srow) * K + sw * 8;
  const size_t aoff1 = aoff0 + (size_t)64 * K;
  const size_t boff0 = (size_t)(bx * 128 + srow) * K + sw * 8;
  const size_t boff1 = boff0 + (size_t)64 * K;
  const int d0 = wid * 512;          // LDS dest (u16 idx), wave-uniform
  const int d1 = 2048 + wid * 512;

  // fragment read offsets (u16 idx), swizzle-matched
  const int wm = wid >> 1, wn = wid & 1;
  const int frow = lane & 15, fsl = lane >> 4;
  int offA[4], offB[4];
#pragma unroll
  for (int i = 0; i < 4; ++i) {
    const int ra = wm * 64 + i * 16 + frow;
    offA[i] = ra * 32 + ((fsl ^ ((ra >> 1) & 3)) * 8);
    const int rb = wn * 64 + i * 16 + frow;
    offB[i] = rb * 32 + ((fsl ^ ((rb >> 1) & 3)) * 8);
  }

  f32x4 acc[4][4];
#pragma unroll
  for (int i = 0; i < 4; ++i)
#pragma unroll
    for (int j = 0; j < 4; ++j)
#pragma unroll
      for (int q = 0; q < 4; ++q) acc[i][j][q] = 0.f;

  for (int k0 = 0; k0 < K; k0 += 32) {
    __syncthreads();  // previous compute done before overwriting LDS
    gload16(Ah + aoff0 + k0, &sAh[d0]);
    gload16(Ah + aoff1 + k0, &sAh[d1]);
    gload16(Al + aoff0 + k0, &sAl[d0]);
    gload16(Al + aoff1 + k0, &sAl[d1]);
    gload16(Bh + boff0 + k0, &sBh[d0]);
    gload16(Bh + boff1 + k0, &sBh[d1]);
    gload16(Bl + boff0 + k0, &sBl[d0]);
    gload16(Bl + boff1 + k0, &sBl[d1]);
    __syncthreads();  // compiler drains vmcnt(0) before barrier

    short8 bh[4], bl[4];
#pragma unroll
    for (int j = 0; j < 4; ++j) {
      bh[j] = *(const short8*)&sBh[offB[j]];
      bl[j] = *(const short8*)&sBl[offB[j]];
    }
#pragma unroll
    for (int i = 0; i < 4; ++i) {
      const short8 ah = *(const short8*)&sAh[offA[i]];
      const short8 al = *(const short8*)&sAl[offA[i]];
#pragma unroll
      for (int j = 0; j < 4; ++j) {
        acc[i][j] = __builtin_amdgcn_mfma_f32_16x16x32_bf16(ah, bh[j], acc[i][j], 0, 0, 0);
        acc[i][j] = __builtin_amdgcn_mfma_f32_16x16x32_bf16(ah, bl[j], acc[i][j], 0, 0, 0);
        acc[i][j] = __builtin_amdgcn_mfma_f32_16x16x32_bf16(al, bh[j], acc[i][j], 0, 0, 0);
      }
    }
  }

  // epilogue: C/D layout col=lane&15, row=(lane>>4)*4+q  [m89-verified]
  const int crow0 = by * 128 + wm * 64 + (lane >> 4) * 4;
  const int ccol0 = bx * 128 + wn * 64 + (lane & 15);
#pragma unroll
  for (int i = 0; i < 4; ++i)
#pragma unroll
    for (int j = 0; j < 4; ++j) {
      float* cp = C + (size_t)(crow0 + i * 16) * N + ccol0 + j * 16;
#pragma unroll
      for (int q = 0; q < 4; ++q) cp[(size_t)q * N] = acc[i][j][q];
    }
}

// ---------------------------------------------------------------------------
// one-time input conversions
// ---------------------------------------------------------------------------
__global__ __launch_bounds__(256)
void split4_f32(const float* __restrict__ in, u16* __restrict__ hi,
                u16* __restrict__ lo, int n4) {
  const int i = blockIdx.x * 256 + threadIdx.x;
  if (i >= n4) return;
  const float4 v = ((const float4*)in)[i];
  u16 h0 = f2bf(v.x), h1 = f2bf(v.y), h2 = f2bf(v.z), h3 = f2bf(v.w);
  u16 l0 = f2bf(v.x - bf2f(h0)), l1 = f2bf(v.y - bf2f(h1));
  u16 l2 = f2bf(v.z - bf2f(h2)), l3 = f2bf(v.w - bf2f(h3));
  uint2 hp, lp;
  hp.x = (u32)h0 | ((u32)h1 << 16); hp.y = (u32)h2 | ((u32)h3 << 16);
  lp.x = (u32)l0 | ((u32)l1 << 16); lp.y = (u32)l2 | ((u32)l3 << 16);
  ((uint2*)hi)[i] = hp;
  ((uint2*)lo)[i] = lp;
}

// W[K][N] fp32 -> WT_hi/lo[N][K] bf16 (transposed so GEMM B-frags are K-contig)
__global__ __launch_bounds__(256)
void split_w_t(const float* __restrict__ W, u16* __restrict__ Th,
               u16* __restrict__ Tl, int K, int N) {
  const int idx = blockIdx.x * 256 + threadIdx.x;
  if (idx >= K * N) return;
  const int k = idx / N, n = idx - k * N;
  const float x = W[idx];
  const u16 h = f2bf(x);
  Th[(size_t)n * K + k] = h;
  Tl[(size_t)n * K + k] = f2bf(x - bf2f(h));
}

__global__ __launch_bounds__(256)
void zero_f32(float* __restrict__ p, int n) {
  const int i = blockIdx.x * 256 + threadIdx.x;
  if (i < n) p[i] = 0.f;
}

// ---------------------------------------------------------------------------
__device__ __forceinline__ float sig(float x) { return 1.f / (1.f + __expf(-x)); }

// Layer-0 scan over one chunk; emits h1 directly as split bf16 (GEMM1's A).
// Group-of-4 software pipeline: next group's 12 loads issue before compute.
__global__ __launch_bounds__(256)
void sru_scan0_chunk(const float* __restrict__ U, const float* __restrict__ v,
                     const float* __restrict__ bias, u16* __restrict__ h1h,
                     u16* __restrict__ h1l, float* __restrict__ cstate, int Tc) {
  const int j = blockIdx.x * 256 + threadIdx.x;   // 0 .. BATCH*HID-1
  const int b = j >> 9, h = j & (HID - 1);
  const float vf = v[h], vr = v[HID + h];
  const float bf = bias[h], br = bias[HID + h];

  const float* p = U + (size_t)b * (3 * HID) + h;
  const size_t sT = (size_t)BATCH * 3 * HID;
  u16* ph = h1h + (size_t)b * HID + h;
  u16* pl = h1l + (size_t)b * HID + h;
  const size_t sH = (size_t)BATCH * HID;

  float c = cstate[j];
  float cu[12];
#pragma unroll
  for (int q = 0; q < 4; ++q) {
    cu[3 * q + 0] = p[q * sT];
    cu[3 * q + 1] = p[q * sT + HID];
    cu[3 * q + 2] = p[q * sT + 2 * HID];
  }
  const int NG = Tc >> 2;
  for (int g = 0; g < NG; ++g) {
    float nx[12];
    const bool has = (g + 1 < NG);
    if (has) {
      const float* pn = p + 4 * sT;
#pragma unroll
      for (int q = 0; q < 4; ++q) {
        nx[3 * q + 0] = pn[q * sT];
        nx[3 * q + 1] = pn[q * sT + HID];
        nx[3 * q + 2] = pn[q * sT + 2 * HID];
      }
    }
#pragma unroll
    for (int q = 0; q < 4; ++q) {
      const float u0 = cu[3 * q], u1 = cu[3 * q + 1], u2 = cu[3 * q + 2];
      const float f = sig(u1 + vf * c + bf);
      const float r = sig(u2 + vr * c + br);
      c = f * c + (1.f - f) * u0;
      const float hv = r * c;
      const u16 hh = f2bf(hv);
      ph[(size_t)(g * 4 + q) * sH] = hh;
      pl[(size_t)(g * 4 + q) * sH] = f2bf(hv - bf2f(hh));
    }
    p += 4 * sT;
    if (has) {
#pragma unroll
      for (int i = 0; i < 12; ++i) cu[i] = nx[i];
    }
  }
  cstate[j] = c;
}

// Layer-1 scan: only u0/u1 needed except the single global last step.
__global__ __launch_bounds__(256)
void sru_scan1_chunk(const float* __restrict__ U, const float* __restrict__ v,
                     const float* __restrict__ bias, float* __restrict__ cstate,
                     float* __restrict__ hlast, int Tc, int lastT) {
  const int j = blockIdx.x * 256 + threadIdx.x;
  const int b = j >> 9, h = j & (HID - 1);
  const float vf = v[h], vr = v[HID + h];
  const float bf = bias[h], br = bias[HID + h];

  const float* p = U + (size_t)b * (3 * HID) + h;
  const size_t sT = (size_t)BATCH * 3 * HID;

  float c = cstate[j];
  float cu[8];
#pragma unroll
  for (int q = 0; q < 4; ++q) {
    cu[2 * q + 0] = p[q * sT];
    cu[2 * q + 1] = p[q * sT + HID];
  }
  const int NG = Tc >> 2;
  for (int g = 0; g < NG; ++g) {
    float nx[8];
    const bool has = (g + 1 < NG);
    if (has) {
      const float* pn = p + 4 * sT;
#pragma unroll
      for (int q = 0; q < 4; ++q) {
        nx[2 * q + 0] = pn[q * sT];
        nx[2 * q + 1] = pn[q * sT + HID];
      }
    }
#pragma unroll
    for (int q = 0; q < 4; ++q) {
      const float u0 = cu[2 * q], u1 = cu[2 * q + 1];
      const float f = sig(u1 + vf * c + bf);
      const float cn = f * c + (1.f - f) * u0;
      if (g * 4 + q == lastT) {            // uniform; true once per sequence
        const float u2 = p[q * sT + 2 * HID];
        const float r = sig(u2 + vr * c + br);
        hlast[j] = r * cn;
      }
      c = cn;
    }
    p += 4 * sT;
    if (has) {
#pragma unroll
      for (int i = 0; i < 8; ++i) cu[i] = nx[i];
    }
  }
  cstate[j] = c;
}

// ---------------------------------------------------------------------------
__global__ __launch_bounds__(256)
void fc_head(const float* __restrict__ h, const float* __restrict__ w,
             const float* __restrict__ bias, float* __restrict__ out) {
  const int gid = blockIdx.x * 256 + threadIdx.x;
  const int wv = gid >> 6, lane = threadIdx.x & 63;
  if (wv >= BATCH * NOUT) return;
  const int b = wv / NOUT, o = wv % NOUT;
  float s = 0.f;
#pragma unroll
  for (int k = lane; k < HID; k += 64)
    s += h[(size_t)b * HID + k] * w[(size_t)o * HID + k];
#pragma unroll
  for (int off = 32; off > 0; off >>= 1) s += __shfl_down(s, off);
  if (lane == 0) out[(size_t)b * NOUT + o] = s + bias[o];
}

// ---------------------------------------------------------------------------
extern "C" void kernel_launch(void* const* d_in, const int* in_sizes, int n_in,
                              void* d_out, int out_size, void* d_ws, size_t ws_size,
                              hipStream_t stream) {
  const float* x   = (const float*)d_in[0];
  const float* W0  = (const float*)d_in[1];
  const float* v0  = (const float*)d_in[2];
  const float* b0  = (const float*)d_in[3];
  const float* W1  = (const float*)d_in[4];
  const float* v1  = (const float*)d_in[5];
  const float* b1  = (const float*)d_in[6];
  const float* fcw = (const float*)d_in[7];
  const float* fcb = (const float*)d_in[8];
  float* out = (float*)d_out;

  const size_t nX = (size_t)L_SEQ * BATCH * DIN;       // 8.39M
  const size_t nW0 = (size_t)DIN * 3 * HID;
  const size_t nW1 = (size_t)HID * 3 * HID;

  // largest Tc whose footprint fits ws_size (Tc=128 -> ~172 MB)
  int Tc = 128;
  for (;;) {
    size_t f32e = (size_t)Tc * BATCH * 3 * HID + 3 * (size_t)BATCH * HID;
    size_t u16e = 2 * nX + 2 * (size_t)Tc * BATCH * HID + 2 * nW0 + 2 * nW1;
    if (f32e * 4 + u16e * 2 + 1024 <= ws_size || Tc <= 8) break;
    Tc >>= 1;
  }
  const int NC = L_SEQ / Tc;
  const int Mc = Tc * BATCH;

  // workspace layout: f32 first, then u16 arrays
  float* U0c = (float*)d_ws;                            // Mc*3H f32 (both layers)
  float* c0  = U0c + (size_t)Mc * 3 * HID;
  float* c1  = c0 + (size_t)BATCH * HID;
  float* h2  = c1 + (size_t)BATCH * HID;
  u16* xs_h  = (u16*)(h2 + (size_t)BATCH * HID);
  u16* xs_l  = xs_h + nX;
  u16* h1_h  = xs_l + nX;
  u16* h1_l  = h1_h + (size_t)Mc * HID;
  u16* w0t_h = h1_l + (size_t)Mc * HID;
  u16* w0t_l = w0t_h + nW0;
  u16* w1t_h = w0t_l + nW0;
  u16* w1t_l = w1t_h + nW1;

  const int scan_grid = (BATCH * HID) / 256;            // 256
  const int g0_grid = (Mc / 128) * (3 * HID / 128);     // Tc*12
  const int fc_grid = (BATCH * NOUT * 64 + 255) / 256;

  // one-time conversions + state zeroing
  zero_f32<<<(2 * BATCH * HID) / 256, 256, 0, stream>>>(c0, 2 * BATCH * HID);
  split4_f32<<<(int)(nX / 4 + 255) / 256, 256, 0, stream>>>(x, xs_h, xs_l, (int)(nX / 4));
  split_w_t<<<(int)(nW0 + 255) / 256, 256, 0, stream>>>(W0, w0t_h, w0t_l, DIN, 3 * HID);
  split_w_t<<<(int)(nW1 + 255) / 256, 256, 0, stream>>>(W1, w1t_h, w1t_l, HID, 3 * HID);

  for (int ch = 0; ch < NC; ++ch) {
    const size_t xoff = (size_t)ch * Tc * BATCH * DIN;
    gemm_bf16x3<<<g0_grid, 256, 0, stream>>>(xs_h + xoff, xs_l + xoff,
                                             w0t_h, w0t_l, U0c, Mc, 3 * HID, DIN);
    sru_scan0_chunk<<<scan_grid, 256, 0, stream>>>(U0c, v0, b0, h1_h, h1_l, c0, Tc);
    gemm_bf16x3<<<g0_grid, 256, 0, stream>>>(h1_h, h1_l,
                                             w1t_h, w1t_l, U0c, Mc, 3 * HID, HID);
    sru_scan1_chunk<<<scan_grid, 256, 0, stream>>>(
        U0c, v1, b1, c1, h2, Tc, (ch == NC - 1) ? Tc - 1 : -1);
  }
  fc_head<<<fc_grid, 256, 0, stream>>>(h2, fcw, fcb, out);
}

// Round 4
// 712.532 us; speedup vs baseline: 2.8000x; 1.0775x over previous
//
#include <hip/hip_runtime.h>
#include <math.h>

#define L_SEQ 512
#define BATCH 128
#define DIN   128
#define HID   512
#define NOUT  5

typedef unsigned short u16;
typedef unsigned int   u32;
typedef __attribute__((ext_vector_type(8))) short short8;
typedef __attribute__((ext_vector_type(4))) float f32x4;

// ---------------------------------------------------------------------------
// bf16 split helpers (RNE).
// ---------------------------------------------------------------------------
__device__ __forceinline__ u16 f2bf(float x) {
  u32 u = __float_as_uint(x);
  return (u16)((u + 0x7fffu + ((u >> 16) & 1u)) >> 16);
}
__device__ __forceinline__ float bf2f(u16 s) {
  return __uint_as_float(((u32)s) << 16);
}
__device__ __forceinline__ void gload16(const void* g, void* l) {
  __builtin_amdgcn_global_load_lds(
      (const __attribute__((address_space(1))) u32*)g,
      (__attribute__((address_space(3))) u32*)l, 16, 0, 0);
}

// ---------------------------------------------------------------------------
// 8-phase-schedule split-bf16 MFMA GEMM (m201 template adapted to bf16x3):
//   C[M,N] = A[M,K] * BT[N,K]^T  via Ah*Bh + Ah*Bl + Al*Bh.
// BM=256, BN=128, BK=32, 8 waves (4Mx2N, per-wave 64x64), triple-buffered
// LDS (144 KB) with counted vmcnt(6) at tile boundaries (T3+T4) and
// setprio around MFMA clusters (T5). Fragment swizzle identical to the
// R3-verified kernel (0 bank conflicts, absmax 7.6e-6).
// NBX = number of 128-wide output column panels to compute (u2-skip).
// ---------------------------------------------------------------------------
#define R_AH 0
#define R_AL 8192
#define R_BH 16384
#define R_BL 20480
#define BUFSZ 24576u   // u16 per buffer (48 KB)

__global__ __launch_bounds__(512, 1)
void gemm_bf16x3_8ph(const u16* __restrict__ Ah, const u16* __restrict__ Al,
                     const u16* __restrict__ Bh, const u16* __restrict__ Bl,
                     float* __restrict__ C, int N, int K, int NBX) {
  __shared__ u16 lds[3 * BUFSZ];   // 144 KB

  const int NT = K >> 5;           // K-tiles of 32
  const int nwg = gridDim.x;
  int bid = blockIdx.x;
  if ((nwg & 7) == 0) {            // bijective XCD swizzle
    const int cpx = nwg >> 3;
    bid = (bid & 7) * cpx + (bid >> 3);
  }
  const int bx = bid % NBX, by = bid / NBX;

  const int tid = threadIdx.x;
  const int w = tid >> 6, lane = tid & 63;

  // ---- staging addressing (pre-swizzled global source, linear LDS dest) ----
  const int srow = lane >> 2;            // 0..15 within wave's 16-row slab
  const int sslot = lane & 3;
  const int ra0 = w * 16 + srow;         // A local row, load q=0 (0..127)
  const int ra1 = 128 + ra0;             // A local row, load q=1
  const int swA0 = sslot ^ ((ra0 >> 1) & 3);
  const int swA1 = sslot ^ ((ra1 >> 1) & 3);
  const u16* pAh0 = Ah + (size_t)(by * 256 + ra0) * K + swA0 * 8;
  const u16* pAh1 = Ah + (size_t)(by * 256 + ra1) * K + swA1 * 8;
  const u16* pAl0 = Al + (size_t)(by * 256 + ra0) * K + swA0 * 8;
  const u16* pAl1 = Al + (size_t)(by * 256 + ra1) * K + swA1 * 8;
  const u16* pBh0 = Bh + (size_t)(bx * 128 + ra0) * K + swA0 * 8;
  const u16* pBl0 = Bl + (size_t)(bx * 128 + ra0) * K + swA0 * 8;
  const int dA0 = (w * 16) * 32;         // wave-uniform LDS dest (u16)
  const int dA1 = (128 + w * 16) * 32;

  // ---- fragment read offsets (u16, swizzle-matched; R3-verified) ----
  const int wm = w >> 1, wn = w & 1;
  const int frow = lane & 15, fsl = lane >> 4;
  int offA[4], offB[4];
#pragma unroll
  for (int i = 0; i < 4; ++i) {
    const int ra = wm * 64 + i * 16 + frow;
    offA[i] = ra * 32 + ((fsl ^ ((ra >> 1) & 3)) * 8);
    const int rb = wn * 64 + i * 16 + frow;
    offB[i] = rb * 32 + ((fsl ^ ((rb >> 1) & 3)) * 8);
  }

  f32x4 acc[4][4];
#pragma unroll
  for (int i = 0; i < 4; ++i)
#pragma unroll
    for (int j = 0; j < 4; ++j)
#pragma unroll
      for (int q = 0; q < 4; ++q) acc[i][j][q] = 0.f;

#define STAGE_A0(ks, stg) do { \
    gload16(pAh0 + (ks), &lds[(stg) + R_AH + dA0]); \
    gload16(pAl0 + (ks), &lds[(stg) + R_AL + dA0]); } while (0)
#define STAGE_A1(ks, stg) do { \
    gload16(pAh1 + (ks), &lds[(stg) + R_AH + dA1]); \
    gload16(pAl1 + (ks), &lds[(stg) + R_AL + dA1]); } while (0)
#define STAGE_BH(ks, stg) gload16(pBh0 + (ks), &lds[(stg) + R_BH + dA0])
#define STAGE_BL(ks, stg) gload16(pBl0 + (ks), &lds[(stg) + R_BL + dA0])

  // prologue: fully stage tile 0 -> buf0, tile 1 -> buf1 (12 loads)
  STAGE_A0(0, 0u); STAGE_A1(0, 0u); STAGE_BH(0, 0u); STAGE_BL(0, 0u);
  STAGE_A0(32, BUFSZ); STAGE_A1(32, BUFSZ); STAGE_BH(32, BUFSZ); STAGE_BL(32, BUFSZ);
  asm volatile("s_waitcnt vmcnt(6)" ::: "memory");   // tile 0 resident
  __builtin_amdgcn_s_barrier();

  unsigned bufs0 = 0, bufs1 = BUFSZ, bufs2 = 2 * BUFSZ;

#define PHASE(i, STAGE_STMT, TAIL) do { \
    const short8 a_h = *(const short8*)&lds[bufs0 + R_AH + offA[i]]; \
    const short8 a_l = *(const short8*)&lds[bufs0 + R_AL + offA[i]]; \
    STAGE_STMT; \
    __builtin_amdgcn_s_barrier(); \
    asm volatile("s_waitcnt lgkmcnt(0)" ::: "memory"); \
    __builtin_amdgcn_sched_barrier(0); \
    __builtin_amdgcn_s_setprio(1); \
    _Pragma("unroll") \
    for (int j = 0; j < 4; ++j) { \
      acc[i][j] = __builtin_amdgcn_mfma_f32_16x16x32_bf16(a_h, bh[j], acc[i][j], 0, 0, 0); \
      acc[i][j] = __builtin_amdgcn_mfma_f32_16x16x32_bf16(a_h, bl[j], acc[i][j], 0, 0, 0); \
      acc[i][j] = __builtin_amdgcn_mfma_f32_16x16x32_bf16(a_l, bh[j], acc[i][j], 0, 0, 0); \
    } \
    __builtin_amdgcn_s_setprio(0); \
    TAIL; \
    __builtin_amdgcn_s_barrier(); \
  } while (0)

  for (int t = 0; t < NT; ++t) {
    const int ks = (t + 2) * 32;
    const bool st = (t + 2) < NT;

    // phase 0: all B frags + A row 0
    short8 bh[4], bl[4];
#pragma unroll
    for (int j = 0; j < 4; ++j) {
      bh[j] = *(const short8*)&lds[bufs0 + R_BH + offB[j]];
      bl[j] = *(const short8*)&lds[bufs0 + R_BL + offB[j]];
    }
    PHASE(0, if (st) STAGE_A0(ks, bufs2), );
    // phase 1
    PHASE(1, if (st) STAGE_A1(ks, bufs2), );
    // phase 2
    PHASE(2, if (st) STAGE_BH(ks, bufs2), );
    // phase 3 + tile boundary: counted vmcnt (never 0 in steady state)
    PHASE(3, if (st) STAGE_BL(ks, bufs2),
          if (t < NT - 2) { asm volatile("s_waitcnt vmcnt(6)" ::: "memory"); }
          else if (t == NT - 2) { asm volatile("s_waitcnt vmcnt(0)" ::: "memory"); });

    const unsigned tmp = bufs0; bufs0 = bufs1; bufs1 = bufs2; bufs2 = tmp;
  }
#undef PHASE
#undef STAGE_A0
#undef STAGE_A1
#undef STAGE_BH
#undef STAGE_BL

  // epilogue: C/D layout col=lane&15, row=(lane>>4)*4+q  [R3-verified]
  const int crow0 = by * 256 + wm * 64 + (lane >> 4) * 4;
  const int ccol0 = bx * 128 + wn * 64 + (lane & 15);
#pragma unroll
  for (int i = 0; i < 4; ++i)
#pragma unroll
    for (int j = 0; j < 4; ++j) {
      float* cp = C + (size_t)(crow0 + i * 16) * N + ccol0 + j * 16;
#pragma unroll
      for (int q = 0; q < 4; ++q) cp[(size_t)q * N] = acc[i][j][q];
    }
}

// ---------------------------------------------------------------------------
// one-time input conversions
// ---------------------------------------------------------------------------
__global__ __launch_bounds__(256)
void split4_f32(const float* __restrict__ in, u16* __restrict__ hi,
                u16* __restrict__ lo, int n4) {
  const int i = blockIdx.x * 256 + threadIdx.x;
  if (i >= n4) return;
  const float4 v = ((const float4*)in)[i];
  u16 h0 = f2bf(v.x), h1 = f2bf(v.y), h2 = f2bf(v.z), h3 = f2bf(v.w);
  u16 l0 = f2bf(v.x - bf2f(h0)), l1 = f2bf(v.y - bf2f(h1));
  u16 l2 = f2bf(v.z - bf2f(h2)), l3 = f2bf(v.w - bf2f(h3));
  uint2 hp, lp;
  hp.x = (u32)h0 | ((u32)h1 << 16); hp.y = (u32)h2 | ((u32)h3 << 16);
  lp.x = (u32)l0 | ((u32)l1 << 16); lp.y = (u32)l2 | ((u32)l3 << 16);
  ((uint2*)hi)[i] = hp;
  ((uint2*)lo)[i] = lp;
}

// W[K][N] fp32 -> WT_hi/lo[N][K] bf16 (transposed: GEMM B-frags K-contig)
__global__ __launch_bounds__(256)
void split_w_t(const float* __restrict__ W, u16* __restrict__ Th,
               u16* __restrict__ Tl, int K, int N) {
  const int idx = blockIdx.x * 256 + threadIdx.x;
  if (idx >= K * N) return;
  const int k = idx / N, n = idx - k * N;
  const float x = W[idx];
  const u16 h = f2bf(x);
  Th[(size_t)n * K + k] = h;
  Tl[(size_t)n * K + k] = f2bf(x - bf2f(h));
}

__global__ __launch_bounds__(256)
void zero_f32(float* __restrict__ p, int n) {
  const int i = blockIdx.x * 256 + threadIdx.x;
  if (i < n) p[i] = 0.f;
}

// ---------------------------------------------------------------------------
__device__ __forceinline__ float sig(float x) { return 1.f / (1.f + __expf(-x)); }

__global__ __launch_bounds__(256)
void sru_scan0_chunk(const float* __restrict__ U, const float* __restrict__ v,
                     const float* __restrict__ bias, u16* __restrict__ h1h,
                     u16* __restrict__ h1l, float* __restrict__ cstate, int Tc) {
  const int j = blockIdx.x * 256 + threadIdx.x;
  const int b = j >> 9, h = j & (HID - 1);
  const float vf = v[h], vr = v[HID + h];
  const float bf = bias[h], br = bias[HID + h];

  const float* p = U + (size_t)b * (3 * HID) + h;
  const size_t sT = (size_t)BATCH * 3 * HID;
  u16* ph = h1h + (size_t)b * HID + h;
  u16* pl = h1l + (size_t)b * HID + h;
  const size_t sH = (size_t)BATCH * HID;

  float c = cstate[j];
  float cu[12];
#pragma unroll
  for (int q = 0; q < 4; ++q) {
    cu[3 * q + 0] = p[q * sT];
    cu[3 * q + 1] = p[q * sT + HID];
    cu[3 * q + 2] = p[q * sT + 2 * HID];
  }
  const int NG = Tc >> 2;
  for (int g = 0; g < NG; ++g) {
    float nx[12];
    const bool has = (g + 1 < NG);
    if (has) {
      const float* pn = p + 4 * sT;
#pragma unroll
      for (int q = 0; q < 4; ++q) {
        nx[3 * q + 0] = pn[q * sT];
        nx[3 * q + 1] = pn[q * sT + HID];
        nx[3 * q + 2] = pn[q * sT + 2 * HID];
      }
    }
#pragma unroll
    for (int q = 0; q < 4; ++q) {
      const float u0 = cu[3 * q], u1 = cu[3 * q + 1], u2 = cu[3 * q + 2];
      const float f = sig(u1 + vf * c + bf);
      const float r = sig(u2 + vr * c + br);
      c = f * c + (1.f - f) * u0;
      const float hv = r * c;
      const u16 hh = f2bf(hv);
      ph[(size_t)(g * 4 + q) * sH] = hh;
      pl[(size_t)(g * 4 + q) * sH] = f2bf(hv - bf2f(hh));
    }
    p += 4 * sT;
    if (has) {
#pragma unroll
      for (int i = 0; i < 12; ++i) cu[i] = nx[i];
    }
  }
  cstate[j] = c;
}

__global__ __launch_bounds__(256)
void sru_scan1_chunk(const float* __restrict__ U, const float* __restrict__ v,
                     const float* __restrict__ bias, float* __restrict__ cstate,
                     float* __restrict__ hlast, int Tc, int lastT) {
  const int j = blockIdx.x * 256 + threadIdx.x;
  const int b = j >> 9, h = j & (HID - 1);
  const float vf = v[h], vr = v[HID + h];
  const float bf = bias[h], br = bias[HID + h];

  const float* p = U + (size_t)b * (3 * HID) + h;
  const size_t sT = (size_t)BATCH * 3 * HID;

  float c = cstate[j];
  float cu[8];
#pragma unroll
  for (int q = 0; q < 4; ++q) {
    cu[2 * q + 0] = p[q * sT];
    cu[2 * q + 1] = p[q * sT + HID];
  }
  const int NG = Tc >> 2;
  for (int g = 0; g < NG; ++g) {
    float nx[8];
    const bool has = (g + 1 < NG);
    if (has) {
      const float* pn = p + 4 * sT;
#pragma unroll
      for (int q = 0; q < 4; ++q) {
        nx[2 * q + 0] = pn[q * sT];
        nx[2 * q + 1] = pn[q * sT + HID];
      }
    }
#pragma unroll
    for (int q = 0; q < 4; ++q) {
      const float u0 = cu[2 * q], u1 = cu[2 * q + 1];
      const float f = sig(u1 + vf * c + bf);
      const float cn = f * c + (1.f - f) * u0;
      if (g * 4 + q == lastT) {
        const float u2 = p[q * sT + 2 * HID];
        const float r = sig(u2 + vr * c + br);
        hlast[j] = r * cn;
      }
      c = cn;
    }
    p += 4 * sT;
    if (has) {
#pragma unroll
      for (int i = 0; i < 8; ++i) cu[i] = nx[i];
    }
  }
  cstate[j] = c;
}

// ---------------------------------------------------------------------------
__global__ __launch_bounds__(256)
void fc_head(const float* __restrict__ h, const float* __restrict__ w,
             const float* __restrict__ bias, float* __restrict__ out) {
  const int gid = blockIdx.x * 256 + threadIdx.x;
  const int wv = gid >> 6, lane = threadIdx.x & 63;
  if (wv >= BATCH * NOUT) return;
  const int b = wv / NOUT, o = wv % NOUT;
  float s = 0.f;
#pragma unroll
  for (int k = lane; k < HID; k += 64)
    s += h[(size_t)b * HID + k] * w[(size_t)o * HID + k];
#pragma unroll
  for (int off = 32; off > 0; off >>= 1) s += __shfl_down(s, off);
  if (lane == 0) out[(size_t)b * NOUT + o] = s + bias[o];
}

// ---------------------------------------------------------------------------
extern "C" void kernel_launch(void* const* d_in, const int* in_sizes, int n_in,
                              void* d_out, int out_size, void* d_ws, size_t ws_size,
                              hipStream_t stream) {
  const float* x   = (const float*)d_in[0];
  const float* W0  = (const float*)d_in[1];
  const float* v0  = (const float*)d_in[2];
  const float* b0  = (const float*)d_in[3];
  const float* W1  = (const float*)d_in[4];
  const float* v1  = (const float*)d_in[5];
  const float* b1  = (const float*)d_in[6];
  const float* fcw = (const float*)d_in[7];
  const float* fcb = (const float*)d_in[8];
  float* out = (float*)d_out;

  const size_t nX = (size_t)L_SEQ * BATCH * DIN;
  const size_t nW0 = (size_t)DIN * 3 * HID;
  const size_t nW1 = (size_t)HID * 3 * HID;

  // largest Tc whose footprint fits ws_size (Tc=128 -> ~172 MB)
  int Tc = 128;
  for (;;) {
    size_t f32e = (size_t)Tc * BATCH * 3 * HID + 3 * (size_t)BATCH * HID;
    size_t u16e = 2 * nX + 2 * (size_t)Tc * BATCH * HID + 2 * nW0 + 2 * nW1;
    if (f32e * 4 + u16e * 2 + 1024 <= ws_size || Tc <= 8) break;
    Tc >>= 1;
  }
  const int NC = L_SEQ / Tc;
  const int Mc = Tc * BATCH;

  float* U0c = (float*)d_ws;
  float* c0  = U0c + (size_t)Mc * 3 * HID;
  float* c1  = c0 + (size_t)BATCH * HID;
  float* h2  = c1 + (size_t)BATCH * HID;
  u16* xs_h  = (u16*)(h2 + (size_t)BATCH * HID);
  u16* xs_l  = xs_h + nX;
  u16* h1_h  = xs_l + nX;
  u16* h1_l  = h1_h + (size_t)Mc * HID;
  u16* w0t_h = h1_l + (size_t)Mc * HID;
  u16* w0t_l = w0t_h + nW0;
  u16* w1t_h = w0t_l + nW0;
  u16* w1t_l = w1t_h + nW1;

  const int scan_grid = (BATCH * HID) / 256;
  const int fc_grid = (BATCH * NOUT * 64 + 255) / 256;
  const int grid_full = (Mc / 256) * 12;   // all 3 output panels (u0,u1,u2)
  const int grid_01   = (Mc / 256) * 8;    // u0,u1 only (u2-skip chunks)

  zero_f32<<<(2 * BATCH * HID) / 256, 256, 0, stream>>>(c0, 2 * BATCH * HID);
  split4_f32<<<(int)(nX / 4 + 255) / 256, 256, 0, stream>>>(x, xs_h, xs_l, (int)(nX / 4));
  split_w_t<<<(int)(nW0 + 255) / 256, 256, 0, stream>>>(W0, w0t_h, w0t_l, DIN, 3 * HID);
  split_w_t<<<(int)(nW1 + 255) / 256, 256, 0, stream>>>(W1, w1t_h, w1t_l, HID, 3 * HID);

  for (int ch = 0; ch < NC; ++ch) {
    const bool last = (ch == NC - 1);
    const size_t xoff = (size_t)ch * Tc * BATCH * DIN;
    gemm_bf16x3_8ph<<<grid_full, 512, 0, stream>>>(
        xs_h + xoff, xs_l + xoff, w0t_h, w0t_l, U0c, 3 * HID, DIN, 12);
    sru_scan0_chunk<<<scan_grid, 256, 0, stream>>>(U0c, v0, b0, h1_h, h1_l, c0, Tc);
    // layer-1: u2 only needed on the chunk containing the global last step
    gemm_bf16x3_8ph<<<last ? grid_full : grid_01, 512, 0, stream>>>(
        h1_h, h1_l, w1t_h, w1t_l, U0c, 3 * HID, HID, last ? 12 : 8);
    sru_scan1_chunk<<<scan_grid, 256, 0, stream>>>(
        U0c, v1, b1, c1, h2, Tc, last ? Tc - 1 : -1);
  }
  fc_head<<<fc_grid, 256, 0, stream>>>(h2, fcw, fcb, out);
}

// Round 5
// 679.269 us; speedup vs baseline: 2.9371x; 1.0490x over previous
//
#include <hip/hip_runtime.h>
#include <math.h>

#define L_SEQ 512
#define BATCH 128
#define DIN   128
#define HID   512
#define NOUT  5

typedef unsigned short u16;
typedef unsigned int   u32;
typedef __attribute__((ext_vector_type(8))) short short8;
typedef __attribute__((ext_vector_type(4))) float f32x4;

// ---------------------------------------------------------------------------
// bf16 split helpers (RNE).
// ---------------------------------------------------------------------------
__device__ __forceinline__ u16 f2bf(float x) {
  u32 u = __float_as_uint(x);
  return (u16)((u + 0x7fffu + ((u >> 16) & 1u)) >> 16);
}
__device__ __forceinline__ float bf2f(u16 s) {
  return __uint_as_float(((u32)s) << 16);
}
__device__ __forceinline__ void gload16(const void* g, void* l) {
  __builtin_amdgcn_global_load_lds(
      (const __attribute__((address_space(1))) u32*)g,
      (__attribute__((address_space(3))) u32*)l, 16, 0, 0);
}

// ---------------------------------------------------------------------------
// Split-bf16 MFMA GEMM, m201-proportioned schedule:
//   C[M,N] = A[M,K]*BT[N,K]^T via Ah*Bh + Ah*Bl + Al*Bh.
// Tile 256x256, BK=32, 8 waves (2M x 4N; per-wave 128x64 out), double-buffered
// 128 KB LDS. Per K-tile: 4 phases x 24 MFMA. Stage order per wave/tile
// (2 gload16 each phase): ph0=B rows[q,+16), ph1=B rows[q+16), ph2=A half-rows
// [0,64), ph3=A half-rows [64,128). Waits (per-wave ledger, steady state):
//   end ph1: vmcnt(4)  -> drains prev tile's ph3-A   (consumed in ph2/ph3)
//   end ph3: vmcnt(2)  -> drains next tile's B + ph2-A (consumed in ph0/ph1)
// Never 0 in the main loop. Each wait is followed by s_barrier, making the
// per-wave drains collective before any consumer ds_read.
// ---------------------------------------------------------------------------
#define BUFSZ 32768u   // u16 per buffer (64 KB); regions: Ah 0, Al 8192, Bh 16384, Bl 24576

__global__ __launch_bounds__(512, 2)
void gemm_bf16x3_v2(const u16* __restrict__ Ah, const u16* __restrict__ Al,
                    const u16* __restrict__ Bh, const u16* __restrict__ Bl,
                    float* __restrict__ C, int N, int K, int NBX) {
  __shared__ u16 lds[2 * BUFSZ];   // 128 KB

  const int NT = K >> 5;
  const int nwg = gridDim.x;
  int bid = blockIdx.x;
  if ((nwg & 7) == 0) {            // bijective XCD swizzle (grids % 8 == 0)
    const int cpx = nwg >> 3;
    bid = (bid & 7) * cpx + (bid >> 3);
  }
  const int bx = bid % NBX, by = bid / NBX;

  const int tid = threadIdx.x;
  const int w = tid >> 6, lane = tid & 63;
  const int wm = w >> 2, wn = w & 3;      // 2M x 4N wave grid

  // ---- staging: 8 loads/wave/tile; lane covers 16-row group r16 = lane>>2 ----
  const int r16 = lane >> 2, sl = lane & 3;
  const int bB0 = wn * 64 + wm * 32;      // this wave's B 16-row group (ph0); ph1 = +16
  const int aB0 = wm * 128 + wn * 16;     // this wave's A share base; ph3 = +64

  const int rB0 = bB0 + r16,      rB1 = bB0 + 16 + r16;
  const int rA0 = aB0 + r16,      rA1 = aB0 + 64 + r16;
  const u16* pB0h = Bh + (size_t)(bx * 256 + rB0) * K + ((sl ^ ((rB0 >> 1) & 3)) * 8);
  const u16* pB0l = Bl + (size_t)(bx * 256 + rB0) * K + ((sl ^ ((rB0 >> 1) & 3)) * 8);
  const u16* pB1h = Bh + (size_t)(bx * 256 + rB1) * K + ((sl ^ ((rB1 >> 1) & 3)) * 8);
  const u16* pB1l = Bl + (size_t)(bx * 256 + rB1) * K + ((sl ^ ((rB1 >> 1) & 3)) * 8);
  const u16* pA0h = Ah + (size_t)(by * 256 + rA0) * K + ((sl ^ ((rA0 >> 1) & 3)) * 8);
  const u16* pA0l = Al + (size_t)(by * 256 + rA0) * K + ((sl ^ ((rA0 >> 1) & 3)) * 8);
  const u16* pA1h = Ah + (size_t)(by * 256 + rA1) * K + ((sl ^ ((rA1 >> 1) & 3)) * 8);
  const u16* pA1l = Al + (size_t)(by * 256 + rA1) * K + ((sl ^ ((rA1 >> 1) & 3)) * 8);
  // wave-uniform LDS dests (u16 idx within buffer)
  const int dB = 16384 + bB0 * 32;   // Bh region; Bl = +8192; ph1 = +512
  const int dA = aB0 * 32;           // Ah region; Al = +8192; ph3 = +2048

#define STAGE_P0(ks, sb) do { gload16(pB0h + (ks), &lds[(sb) + dB]); \
                              gload16(pB0l + (ks), &lds[(sb) + dB + 8192]); } while (0)
#define STAGE_P1(ks, sb) do { gload16(pB1h + (ks), &lds[(sb) + dB + 512]); \
                              gload16(pB1l + (ks), &lds[(sb) + dB + 8704]); } while (0)
#define STAGE_P2(ks, sb) do { gload16(pA0h + (ks), &lds[(sb) + dA]); \
                              gload16(pA0l + (ks), &lds[(sb) + dA + 8192]); } while (0)
#define STAGE_P3(ks, sb) do { gload16(pA1h + (ks), &lds[(sb) + dA + 2048]); \
                              gload16(pA1l + (ks), &lds[(sb) + dA + 10240]); } while (0)

  // ---- fragment read offsets (u16, swizzle-matched; R3-verified pattern) ----
  const int frow = lane & 15, fsl = lane >> 4;
  int offA[8], offB[4];
#pragma unroll
  for (int i = 0; i < 8; ++i) {
    const int ra = wm * 128 + i * 16 + frow;
    offA[i] = ra * 32 + ((fsl ^ ((ra >> 1) & 3)) * 8);
  }
#pragma unroll
  for (int j = 0; j < 4; ++j) {
    const int rb = wn * 64 + j * 16 + frow;
    offB[j] = 16384 + rb * 32 + ((fsl ^ ((rb >> 1) & 3)) * 8);
  }

  f32x4 acc[8][4];
#pragma unroll
  for (int i = 0; i < 8; ++i)
#pragma unroll
    for (int j = 0; j < 4; ++j)
#pragma unroll
      for (int q = 0; q < 4; ++q) acc[i][j][q] = 0.f;

  // prologue: stage tile 0 fully, drain, barrier
  STAGE_P0(0, 0u); STAGE_P1(0, 0u); STAGE_P2(0, 0u); STAGE_P3(0, 0u);
  asm volatile("s_waitcnt vmcnt(0)" ::: "memory");
  __builtin_amdgcn_s_barrier();

#define MFMA3(i, j, aa_h, aa_l) \
    acc[i][j] = __builtin_amdgcn_mfma_f32_16x16x32_bf16(aa_h, bh[j], acc[i][j], 0, 0, 0); \
    acc[i][j] = __builtin_amdgcn_mfma_f32_16x16x32_bf16(aa_h, bl[j], acc[i][j], 0, 0, 0); \
    acc[i][j] = __builtin_amdgcn_mfma_f32_16x16x32_bf16(aa_l, bh[j], acc[i][j], 0, 0, 0)

#define PHASE(p, STG, TAIL) do { \
    const short8 ah0 = *(const short8*)&lds[cb + offA[2 * (p)]]; \
    const short8 al0 = *(const short8*)&lds[cb + 8192 + offA[2 * (p)]]; \
    const short8 ah1 = *(const short8*)&lds[cb + offA[2 * (p) + 1]]; \
    const short8 al1 = *(const short8*)&lds[cb + 8192 + offA[2 * (p) + 1]]; \
    STG; \
    __builtin_amdgcn_s_barrier(); \
    asm volatile("s_waitcnt lgkmcnt(0)" ::: "memory"); \
    __builtin_amdgcn_sched_barrier(0); \
    __builtin_amdgcn_s_setprio(1); \
    _Pragma("unroll") \
    for (int j = 0; j < 4; ++j) { \
      acc[2*(p)][j]   = __builtin_amdgcn_mfma_f32_16x16x32_bf16(ah0, bh[j], acc[2*(p)][j], 0, 0, 0); \
      acc[2*(p)+1][j] = __builtin_amdgcn_mfma_f32_16x16x32_bf16(ah1, bh[j], acc[2*(p)+1][j], 0, 0, 0); \
    } \
    _Pragma("unroll") \
    for (int j = 0; j < 4; ++j) { \
      acc[2*(p)][j]   = __builtin_amdgcn_mfma_f32_16x16x32_bf16(ah0, bl[j], acc[2*(p)][j], 0, 0, 0); \
      acc[2*(p)+1][j] = __builtin_amdgcn_mfma_f32_16x16x32_bf16(ah1, bl[j], acc[2*(p)+1][j], 0, 0, 0); \
    } \
    _Pragma("unroll") \
    for (int j = 0; j < 4; ++j) { \
      acc[2*(p)][j]   = __builtin_amdgcn_mfma_f32_16x16x32_bf16(al0, bh[j], acc[2*(p)][j], 0, 0, 0); \
      acc[2*(p)+1][j] = __builtin_amdgcn_mfma_f32_16x16x32_bf16(al1, bh[j], acc[2*(p)+1][j], 0, 0, 0); \
    } \
    __builtin_amdgcn_s_setprio(0); \
    TAIL; \
    __builtin_amdgcn_s_barrier(); \
  } while (0)

  int cb = 0;
  for (int t = 0; t < NT; ++t) {
    const int ks = (t + 1) << 5;
    const bool st = (t + 1) < NT;
    const int sb = cb ^ (int)BUFSZ;

    short8 bh[4], bl[4];
#pragma unroll
    for (int j = 0; j < 4; ++j) {
      bh[j] = *(const short8*)&lds[cb + offB[j]];
      bl[j] = *(const short8*)&lds[cb + 8192 + offB[j]];
    }
    PHASE(0, if (st) STAGE_P0(ks, sb), );
    PHASE(1, if (st) STAGE_P1(ks, sb),
          if (st) { asm volatile("s_waitcnt vmcnt(4)" ::: "memory"); }
          else    { asm volatile("s_waitcnt vmcnt(0)" ::: "memory"); });
    PHASE(2, if (st) STAGE_P2(ks, sb), );
    PHASE(3, if (st) STAGE_P3(ks, sb),
          if (st) { asm volatile("s_waitcnt vmcnt(2)" ::: "memory"); });
    cb = sb;
  }
#undef PHASE
#undef MFMA3
#undef STAGE_P0
#undef STAGE_P1
#undef STAGE_P2
#undef STAGE_P3

  // epilogue: C/D layout col=lane&15, row=(lane>>4)*4+q  [R3-verified]
  const int crow0 = by * 256 + wm * 128 + (lane >> 4) * 4;
  const int ccol0 = bx * 256 + wn * 64 + (lane & 15);
#pragma unroll
  for (int i = 0; i < 8; ++i)
#pragma unroll
    for (int j = 0; j < 4; ++j) {
      float* cp = C + (size_t)(crow0 + i * 16) * N + ccol0 + j * 16;
#pragma unroll
      for (int q = 0; q < 4; ++q) cp[(size_t)q * N] = acc[i][j][q];
    }
}

// ---------------------------------------------------------------------------
// one-time input conversions
// ---------------------------------------------------------------------------
__global__ __launch_bounds__(256)
void split4_f32(const float* __restrict__ in, u16* __restrict__ hi,
                u16* __restrict__ lo, int n4) {
  const int i = blockIdx.x * 256 + threadIdx.x;
  if (i >= n4) return;
  const float4 v = ((const float4*)in)[i];
  u16 h0 = f2bf(v.x), h1 = f2bf(v.y), h2 = f2bf(v.z), h3 = f2bf(v.w);
  u16 l0 = f2bf(v.x - bf2f(h0)), l1 = f2bf(v.y - bf2f(h1));
  u16 l2 = f2bf(v.z - bf2f(h2)), l3 = f2bf(v.w - bf2f(h3));
  uint2 hp, lp;
  hp.x = (u32)h0 | ((u32)h1 << 16); hp.y = (u32)h2 | ((u32)h3 << 16);
  lp.x = (u32)l0 | ((u32)l1 << 16); lp.y = (u32)l2 | ((u32)l3 << 16);
  ((uint2*)hi)[i] = hp;
  ((uint2*)lo)[i] = lp;
}

__global__ __launch_bounds__(256)
void split_w_t(const float* __restrict__ W, u16* __restrict__ Th,
               u16* __restrict__ Tl, int K, int N) {
  const int idx = blockIdx.x * 256 + threadIdx.x;
  if (idx >= K * N) return;
  const int k = idx / N, n = idx - k * N;
  const float x = W[idx];
  const u16 h = f2bf(x);
  Th[(size_t)n * K + k] = h;
  Tl[(size_t)n * K + k] = f2bf(x - bf2f(h));
}

// ---------------------------------------------------------------------------
__device__ __forceinline__ float sig(float x) { return 1.f / (1.f + __expf(-x)); }

__global__ __launch_bounds__(256)
void sru_scan0_chunk(const float* __restrict__ U, const float* __restrict__ v,
                     const float* __restrict__ bias, u16* __restrict__ h1h,
                     u16* __restrict__ h1l, float* __restrict__ cstate, int Tc,
                     int init) {
  const int j = blockIdx.x * 256 + threadIdx.x;
  const int b = j >> 9, h = j & (HID - 1);
  const float vf = v[h], vr = v[HID + h];
  const float bf = bias[h], br = bias[HID + h];

  const float* p = U + (size_t)b * (3 * HID) + h;
  const size_t sT = (size_t)BATCH * 3 * HID;
  u16* ph = h1h + (size_t)b * HID + h;
  u16* pl = h1l + (size_t)b * HID + h;
  const size_t sH = (size_t)BATCH * HID;

  float c = init ? 0.f : cstate[j];
  float cu[12];
#pragma unroll
  for (int q = 0; q < 4; ++q) {
    cu[3 * q + 0] = p[q * sT];
    cu[3 * q + 1] = p[q * sT + HID];
    cu[3 * q + 2] = p[q * sT + 2 * HID];
  }
  const int NG = Tc >> 2;
  for (int g = 0; g < NG; ++g) {
    float nx[12];
    const bool has = (g + 1 < NG);
    if (has) {
      const float* pn = p + 4 * sT;
#pragma unroll
      for (int q = 0; q < 4; ++q) {
        nx[3 * q + 0] = pn[q * sT];
        nx[3 * q + 1] = pn[q * sT + HID];
        nx[3 * q + 2] = pn[q * sT + 2 * HID];
      }
    }
#pragma unroll
    for (int q = 0; q < 4; ++q) {
      const float u0 = cu[3 * q], u1 = cu[3 * q + 1], u2 = cu[3 * q + 2];
      const float f = sig(u1 + vf * c + bf);
      const float r = sig(u2 + vr * c + br);
      c = f * c + (1.f - f) * u0;
      const float hv = r * c;
      const u16 hh = f2bf(hv);
      ph[(size_t)(g * 4 + q) * sH] = hh;
      pl[(size_t)(g * 4 + q) * sH] = f2bf(hv - bf2f(hh));
    }
    p += 4 * sT;
    if (has) {
#pragma unroll
      for (int i = 0; i < 12; ++i) cu[i] = nx[i];
    }
  }
  cstate[j] = c;
}

__global__ __launch_bounds__(256)
void sru_scan1_chunk(const float* __restrict__ U, const float* __restrict__ v,
                     const float* __restrict__ bias, float* __restrict__ cstate,
                     float* __restrict__ hlast, int Tc, int lastT, int init) {
  const int j = blockIdx.x * 256 + threadIdx.x;
  const int b = j >> 9, h = j & (HID - 1);
  const float vf = v[h], vr = v[HID + h];
  const float bf = bias[h], br = bias[HID + h];

  const float* p = U + (size_t)b * (3 * HID) + h;
  const size_t sT = (size_t)BATCH * 3 * HID;

  float c = init ? 0.f : cstate[j];
  float cu[8];
#pragma unroll
  for (int q = 0; q < 4; ++q) {
    cu[2 * q + 0] = p[q * sT];
    cu[2 * q + 1] = p[q * sT + HID];
  }
  const int NG = Tc >> 2;
  for (int g = 0; g < NG; ++g) {
    float nx[8];
    const bool has = (g + 1 < NG);
    if (has) {
      const float* pn = p + 4 * sT;
#pragma unroll
      for (int q = 0; q < 4; ++q) {
        nx[2 * q + 0] = pn[q * sT];
        nx[2 * q + 1] = pn[q * sT + HID];
      }
    }
#pragma unroll
    for (int q = 0; q < 4; ++q) {
      const float u0 = cu[2 * q], u1 = cu[2 * q + 1];
      const float f = sig(u1 + vf * c + bf);
      const float cn = f * c + (1.f - f) * u0;
      if (g * 4 + q == lastT) {
        const float u2 = p[q * sT + 2 * HID];
        const float r = sig(u2 + vr * c + br);
        hlast[j] = r * cn;
      }
      c = cn;
    }
    p += 4 * sT;
    if (has) {
#pragma unroll
      for (int i = 0; i < 8; ++i) cu[i] = nx[i];
    }
  }
  cstate[j] = c;
}

// ---------------------------------------------------------------------------
__global__ __launch_bounds__(256)
void fc_head(const float* __restrict__ h, const float* __restrict__ w,
             const float* __restrict__ bias, float* __restrict__ out) {
  const int gid = blockIdx.x * 256 + threadIdx.x;
  const int wv = gid >> 6, lane = threadIdx.x & 63;
  if (wv >= BATCH * NOUT) return;
  const int b = wv / NOUT, o = wv % NOUT;
  float s = 0.f;
#pragma unroll
  for (int k = lane; k < HID; k += 64)
    s += h[(size_t)b * HID + k] * w[(size_t)o * HID + k];
#pragma unroll
  for (int off = 32; off > 0; off >>= 1) s += __shfl_down(s, off);
  if (lane == 0) out[(size_t)b * NOUT + o] = s + bias[o];
}

// ---------------------------------------------------------------------------
extern "C" void kernel_launch(void* const* d_in, const int* in_sizes, int n_in,
                              void* d_out, int out_size, void* d_ws, size_t ws_size,
                              hipStream_t stream) {
  const float* x   = (const float*)d_in[0];
  const float* W0  = (const float*)d_in[1];
  const float* v0  = (const float*)d_in[2];
  const float* b0  = (const float*)d_in[3];
  const float* W1  = (const float*)d_in[4];
  const float* v1  = (const float*)d_in[5];
  const float* b1  = (const float*)d_in[6];
  const float* fcw = (const float*)d_in[7];
  const float* fcb = (const float*)d_in[8];
  float* out = (float*)d_out;

  const size_t nX = (size_t)L_SEQ * BATCH * DIN;
  const size_t nW0 = (size_t)DIN * 3 * HID;
  const size_t nW1 = (size_t)HID * 3 * HID;

  // largest Tc whose footprint fits ws_size (Tc=128 -> ~174 MB, proven fit)
  int Tc = 128;
  for (;;) {
    size_t f32e = (size_t)Tc * BATCH * 3 * HID + 3 * (size_t)BATCH * HID;
    size_t u16e = 2 * nX + 2 * (size_t)Tc * BATCH * HID + 2 * nW0 + 2 * nW1;
    if (f32e * 4 + u16e * 2 + 1024 <= ws_size || Tc <= 8) break;
    Tc >>= 1;
  }
  const int NC = L_SEQ / Tc;
  const int Mc = Tc * BATCH;

  float* U0c = (float*)d_ws;
  float* c0  = U0c + (size_t)Mc * 3 * HID;
  float* c1  = c0 + (size_t)BATCH * HID;
  float* h2  = c1 + (size_t)BATCH * HID;
  u16* xs_h  = (u16*)(h2 + (size_t)BATCH * HID);
  u16* xs_l  = xs_h + nX;
  u16* h1_h  = xs_l + nX;
  u16* h1_l  = h1_h + (size_t)Mc * HID;
  u16* w0t_h = h1_l + (size_t)Mc * HID;
  u16* w0t_l = w0t_h + nW0;
  u16* w1t_h = w0t_l + nW0;
  u16* w1t_l = w1t_h + nW1;

  const int scan_grid = (BATCH * HID) / 256;
  const int fc_grid = (BATCH * NOUT * 64 + 255) / 256;
  const int grid_full = (Mc / 256) * 6;   // 256x256 tiles over N=1536
  const int grid_01   = (Mc / 256) * 4;   // u0,u1 panels only (N=1024)

  split4_f32<<<(int)(nX / 4 + 255) / 256, 256, 0, stream>>>(x, xs_h, xs_l, (int)(nX / 4));
  split_w_t<<<(int)(nW0 + 255) / 256, 256, 0, stream>>>(W0, w0t_h, w0t_l, DIN, 3 * HID);
  split_w_t<<<(int)(nW1 + 255) / 256, 256, 0, stream>>>(W1, w1t_h, w1t_l, HID, 3 * HID);

  for (int ch = 0; ch < NC; ++ch) {
    const bool last = (ch == NC - 1);
    const size_t xoff = (size_t)ch * Tc * BATCH * DIN;
    gemm_bf16x3_v2<<<grid_full, 512, 0, stream>>>(
        xs_h + xoff, xs_l + xoff, w0t_h, w0t_l, U0c, 3 * HID, DIN, 6);
    sru_scan0_chunk<<<scan_grid, 256, 0, stream>>>(U0c, v0, b0, h1_h, h1_l, c0, Tc,
                                                   ch == 0);
    gemm_bf16x3_v2<<<last ? grid_full : grid_01, 512, 0, stream>>>(
        h1_h, h1_l, w1t_h, w1t_l, U0c, 3 * HID, HID, last ? 6 : 4);
    sru_scan1_chunk<<<scan_grid, 256, 0, stream>>>(
        U0c, v1, b1, c1, h2, Tc, last ? Tc - 1 : -1, ch == 0);
  }
  fc_head<<<fc_grid, 256, 0, stream>>>(h2, fcw, fcb, out);
}